// Round 5
// baseline (315.705 us; speedup 1.0000x reference)
//
#include <hip/hip_runtime.h>

#define EMB 2048
#define UDIM 256
#define KTOT 2304
#define NE 64
#define TOPK 8
#define TPB 32               // tokens per block
#define LP 65                // reduce-slab row stride
#define PLANE (KTOT * NE)    // elements per bf16 W plane (147456)

typedef __attribute__((ext_vector_type(8))) short short8;
typedef __attribute__((ext_vector_type(4))) float f32x4;

__device__ __forceinline__ unsigned short bf16h(float x) {
  unsigned uu = __builtin_bit_cast(unsigned, x);
  return (unsigned short)((uu + 0x7FFFu + ((uu >> 16) & 1u)) >> 16);
}
__device__ __forceinline__ float bf2f(unsigned short s) {
  return __builtin_bit_cast(float, ((unsigned)s) << 16);
}

// ---- prep: W fp32 [2304][64] -> 3 transposed bf16 planes [64][2304] ----
// w = w0 + w1 + w2 + eps, |eps| <= 2^-27 |w|
__global__ __launch_bounds__(256)
void prep_w(const float* __restrict__ W, unsigned short* __restrict__ wt) {
  __shared__ unsigned short t0[64][72], t1[64][72], t2[64][72];
  const int t = threadIdx.x;
  const int kb = blockIdx.x * 64;
#pragma unroll
  for (int i = 0; i < 16; ++i) {
    const int flat = i * 256 + t;
    const int kk = flat >> 6;
    const int nn = flat & 63;
    const float w = W[(size_t)(kb + kk) * NE + nn];  // coalesced
    const unsigned short h0 = bf16h(w);
    const float r1 = w - bf2f(h0);                   // exact in fp32
    const unsigned short h1 = bf16h(r1);
    const float r2 = r1 - bf2f(h1);                  // exact in fp32
    t0[nn][kk] = h0;
    t1[nn][kk] = h1;
    t2[nn][kk] = bf16h(r2);
  }
  __syncthreads();
#pragma unroll
  for (int i = 0; i < 16; ++i) {
    const int flat = i * 256 + t;
    const int nn = flat >> 6;
    const int kk = flat & 63;
    const size_t idx = (size_t)nn * KTOT + kb + kk;  // coalesced
    wt[idx] = t0[nn][kk];
    wt[PLANE + idx] = t1[nn][kk];
    wt[2 * PLANE + idx] = t2[nn][kk];
  }
}

// ---- main: triple-split bf16 MFMA GEMM + softmax + top-8 ----
__global__ __launch_bounds__(512, 4)
void gate_mfma(const float* __restrict__ h, const float* __restrict__ u,
               const unsigned short* __restrict__ wt,
               const float* __restrict__ b, float* __restrict__ out) {
  __shared__ float slab[TPB * LP];  // 8.3 KB

  const int tid = threadIdx.x;
  const int lane = tid & 63;
  const int wid = __builtin_amdgcn_readfirstlane(tid >> 6);
  const int tw = wid & 1;   // token tile (16 tokens)
  const int kq = wid >> 1;  // K-split slice 0..3 (576 k each)
  const int mm = lane & 15; // A: token-in-tile | B: expert-in-tile
  const int q8 = (lane >> 4) * 8;  // k-subgroup offset within frag
  const int tok0 = blockIdx.x * TPB;
  const int token = tok0 + tw * 16 + mm;

  const float* hrow = h + (size_t)token * EMB + q8;
  const float* urow = u + (size_t)token * UDIM + q8;
  const unsigned short* wrow[4];
#pragma unroll
  for (int nt = 0; nt < 4; ++nt)
    wrow[nt] = wt + (size_t)(nt * 16 + mm) * KTOT + q8;

  f32x4 acc[4];
#pragma unroll
  for (int nt = 0; nt < 4; ++nt) acc[nt] = 0.f;

  // one GEMM segment: steps of 32 k; A from xp (fp32), B at k = kw0+s*32
  auto run = [&](const float* __restrict__ xp, int kw0, int nsteps) {
    f32x4 a0 = *(const f32x4*)(xp);
    f32x4 a1 = *(const f32x4*)(xp + 4);
    for (int s = 0; s < nsteps; ++s) {
      f32x4 p0 = 0.f, p1 = 0.f;
      if (s + 1 < nsteps) {                  // A prefetch (HBM stream)
        p0 = *(const f32x4*)(xp + (s + 1) * 32);
        p1 = *(const f32x4*)(xp + (s + 1) * 32 + 4);
      }
      const int kw = kw0 + s * 32;
      // triple-split current A: x = A0 + A1 + A2, err <= 2^-27|x|
      float xs[8] = {a0[0], a0[1], a0[2], a0[3], a1[0], a1[1], a1[2], a1[3]};
      short8 A0, A1, A2;
#pragma unroll
      for (int j = 0; j < 8; ++j) {
        const unsigned short h0 = bf16h(xs[j]);
        const float r1 = xs[j] - bf2f(h0);
        const unsigned short h1 = bf16h(r1);
        const float r2 = r1 - bf2f(h1);
        A0[j] = (short)h0;
        A1[j] = (short)h1;
        A2[j] = (short)bf16h(r2);
      }
      // 4 n-tiles x 6 split terms (shift-sum < 24 bits kept)
#pragma unroll
      for (int nt = 0; nt < 4; ++nt) {
        const unsigned short* wp = wrow[nt] + kw;
        const short8 B0 = *(const short8*)(wp);
        const short8 B1 = *(const short8*)(wp + PLANE);
        const short8 B2 = *(const short8*)(wp + 2 * PLANE);
        acc[nt] = __builtin_amdgcn_mfma_f32_16x16x32_bf16(A0, B0, acc[nt], 0, 0, 0);
        acc[nt] = __builtin_amdgcn_mfma_f32_16x16x32_bf16(A0, B1, acc[nt], 0, 0, 0);
        acc[nt] = __builtin_amdgcn_mfma_f32_16x16x32_bf16(A1, B0, acc[nt], 0, 0, 0);
        acc[nt] = __builtin_amdgcn_mfma_f32_16x16x32_bf16(A1, B1, acc[nt], 0, 0, 0);
        acc[nt] = __builtin_amdgcn_mfma_f32_16x16x32_bf16(A0, B2, acc[nt], 0, 0, 0);
        acc[nt] = __builtin_amdgcn_mfma_f32_16x16x32_bf16(A2, B0, acc[nt], 0, 0, 0);
      }
      a0 = p0;
      a1 = p1;
    }
  };

  const int kw0 = kq * 576;
  if (kq < 3) {
    run(hrow + kw0, kw0, 18);            // pure h: 576 k
  } else {
    run(hrow + 1728, 1728, 10);          // h tail: [1728,2048)
    run(urow, 2048, 8);                  // u: [2048,2304)
  }

  // ---- 4-phase K reduce into slab (D: row=token=(lane>>4)*4+reg, col=expert=mm)
  const int row = tw * 16 + (lane >> 4) * 4;
  for (int ph = 0; ph < 4; ++ph) {
    if (kq == ph) {
#pragma unroll
      for (int nt = 0; nt < 4; ++nt)
#pragma unroll
        for (int r = 0; r < 4; ++r) {
          float* p = &slab[(row + r) * LP + nt * 16 + mm];
          if (ph == 0) *p = acc[nt][r]; else *p += acc[nt][r];
        }
    }
    __syncthreads();
  }

  // ---- epilogue: wave wid handles tokens [4*wid, 4*wid+4); lane = expert ----
  const float bias = b[lane];
#pragma unroll
  for (int tt = 0; tt < 4; ++tt) {
    const int t = wid * 4 + tt;
    float g = slab[t * LP + lane] + bias;

    float m = g;
#pragma unroll
    for (int off = 32; off > 0; off >>= 1)
      m = fmaxf(m, __shfl_xor(m, off));
    float pexp = __expf(g - m);
    float s = pexp;
#pragma unroll
    for (int off = 32; off > 0; off >>= 1)
      s += __shfl_xor(s, off);
    const float pn = pexp / s;

    float vv = pn;
    float topsum = 0.f;
    int sel = 0;
    for (int r = 0; r < TOPK; ++r) {
      float mv = vv;
      int mi = lane;
#pragma unroll
      for (int off = 32; off > 0; off >>= 1) {
        const float ov = __shfl_xor(mv, off);
        const int oi = __shfl_xor(mi, off);
        if (ov > mv || (ov == mv && oi < mi)) { mv = ov; mi = oi; }
      }
      topsum += mv;
      if (lane == mi) { sel = 1; vv = -1.f; }
    }

    out[(size_t)(tok0 + t) * NE + lane] =
        sel ? pn / (topsum + 1e-9f) : 0.f;
  }
}

extern "C" void kernel_launch(void* const* d_in, const int* in_sizes, int n_in,
                              void* d_out, int out_size, void* d_ws, size_t ws_size,
                              hipStream_t stream) {
  const float* h = (const float*)d_in[0];
  const float* u = (const float*)d_in[1];
  const float* W = (const float*)d_in[2];
  const float* b = (const float*)d_in[3];
  float* out = (float*)d_out;

  unsigned short* wt = (unsigned short*)d_ws;  // 3 planes, 884736 B total

  const int n_tokens = in_sizes[0] / EMB;  // 16384

  hipLaunchKernelGGL(prep_w, dim3(KTOT / 64), dim3(256), 0, stream, W, wt);
  hipLaunchKernelGGL(gate_mfma, dim3(n_tokens / TPB), dim3(512), 0, stream,
                     h, u, wt, b, out);
}

// Round 6
// 262.580 us; speedup vs baseline: 1.2023x; 1.2023x over previous
//
#include <hip/hip_runtime.h>

#define EMB 2048
#define UDIM 256
#define KTOT 2304
#define NE 64
#define TOPK 8
#define TPB 32               // tokens per block
#define LP 65                // reduce-slab row stride
#define NSTEP (KTOT / 32)    // 72 k-steps total
#define SSH 6144             // shorts per k-step in wb: 3 planes * 4 nt * 64 lanes * 8

typedef __attribute__((ext_vector_type(8))) short short8;
typedef __attribute__((ext_vector_type(4))) float f32x4;

__device__ __forceinline__ unsigned short bf16h(float x) {
  unsigned uu = __builtin_bit_cast(unsigned, x);
  return (unsigned short)((uu + 0x7FFFu + ((uu >> 16) & 1u)) >> 16);
}
__device__ __forceinline__ float bf2f(unsigned short s) {
  return __builtin_bit_cast(float, ((unsigned)s) << 16);
}

// ---- prep: W fp32 [2304][64] -> triple-split bf16 in MFMA-FRAGMENT order ----
// wb[kstep][plane][nt][lane][j]:  lane = (kk>>3)*16 + (n&15), j = kk&7
// => each wave B-load is base + lane*16B: ONE coalesced dwordx4, 4 lines.
__global__ __launch_bounds__(256)
void prep_w(const float* __restrict__ W, unsigned short* __restrict__ wb) {
  const int flat = blockIdx.x * 256 + threadIdx.x;  // 0..147455
  const int k = flat >> 6;
  const int n = flat & 63;
  const float w = W[flat];  // coalesced read
  const unsigned short h0 = bf16h(w);
  const float r1 = w - bf2f(h0);   // exact in fp32
  const unsigned short h1 = bf16h(r1);
  const float r2 = r1 - bf2f(h1);  // exact in fp32
  const unsigned short h2 = bf16h(r2);

  const int s = k >> 5;
  const int kk = k & 31;
  const int lane = (kk >> 3) * 16 + (n & 15);
  const int j = kk & 7;
  const int nt = n >> 4;
  const size_t base = (size_t)s * SSH + ((size_t)nt * 64 + lane) * 8 + j;
  wb[base] = h0;                    // plane 0
  wb[base + 2048] = h1;             // plane 1 (4*64*8 shorts per plane-step)
  wb[base + 4096] = h2;             // plane 2
}

// ---- main: triple-split bf16 MFMA GEMM + softmax + top-8 ----
__global__ __launch_bounds__(512, 4)
void gate_mfma(const float* __restrict__ h, const float* __restrict__ u,
               const unsigned short* __restrict__ wb,
               const float* __restrict__ b, float* __restrict__ out) {
  __shared__ float slab[TPB * LP];  // 8.3 KB

  const int tid = threadIdx.x;
  const int lane = tid & 63;
  const int wid = __builtin_amdgcn_readfirstlane(tid >> 6);
  const int tw = wid & 1;   // token tile (16 tokens)
  const int kq = wid >> 1;  // K-split slice 0..3 (576 k each)
  const int mm = lane & 15; // A: token-in-tile | B: expert-in-tile
  const int q8 = (lane >> 4) * 8;  // k-subgroup offset within frag
  const int tok0 = blockIdx.x * TPB;
  const int token = tok0 + tw * 16 + mm;

  const float* hrow = h + (size_t)token * EMB + q8;
  const float* urow = u + (size_t)token * UDIM + q8;
  const unsigned short* wlane = wb + (size_t)lane * 8;  // per-lane frag base

  f32x4 acc[4];
#pragma unroll
  for (int nt = 0; nt < 4; ++nt) acc[nt] = 0.f;

  // one GEMM segment: steps of 32 k; A per-lane fp32 (2-step prefetch),
  // B coalesced frag-order dwordx4 (L2-hot), no barriers, vmcnt only.
  auto run = [&](const float* __restrict__ xp, int kw0, int nsteps) {
    f32x4 c0 = *(const f32x4*)(xp);
    f32x4 c1 = *(const f32x4*)(xp + 4);
    f32x4 n0 = 0.f, n1 = 0.f;
    if (nsteps > 1) {
      n0 = *(const f32x4*)(xp + 32);
      n1 = *(const f32x4*)(xp + 36);
    }
    const int as0 = kw0 >> 5;  // absolute k-step index
    for (int s = 0; s < nsteps; ++s) {
      // A prefetch 2 ahead (covers L3 latency)
      f32x4 f0 = 0.f, f1 = 0.f;
      if (s + 2 < nsteps) {
        f0 = *(const f32x4*)(xp + (s + 2) * 32);
        f1 = *(const f32x4*)(xp + (s + 2) * 32 + 4);
      }
      // B frag loads: 12 coalesced dwordx4 (issue first, consumed after conv)
      const unsigned short* ws = wlane + (size_t)(as0 + s) * SSH;
      short8 Bv[3][4];
#pragma unroll
      for (int p = 0; p < 3; ++p)
#pragma unroll
        for (int nt = 0; nt < 4; ++nt)
          Bv[p][nt] = *(const short8*)(ws + (p * 4 + nt) * 512);

      // triple-split current A: x = A0 + A1 + A2, err <= 2^-27|x|
      float xs[8] = {c0[0], c0[1], c0[2], c0[3], c1[0], c1[1], c1[2], c1[3]};
      short8 A0, A1, A2;
#pragma unroll
      for (int j = 0; j < 8; ++j) {
        const unsigned short h0 = bf16h(xs[j]);
        const float r1 = xs[j] - bf2f(h0);
        const unsigned short h1 = bf16h(r1);
        const float r2 = r1 - bf2f(h1);
        A0[j] = (short)h0;
        A1[j] = (short)h1;
        A2[j] = (short)bf16h(r2);
      }
      // 4 n-tiles x 6 split terms
#pragma unroll
      for (int nt = 0; nt < 4; ++nt) {
        acc[nt] = __builtin_amdgcn_mfma_f32_16x16x32_bf16(A0, Bv[0][nt], acc[nt], 0, 0, 0);
        acc[nt] = __builtin_amdgcn_mfma_f32_16x16x32_bf16(A0, Bv[1][nt], acc[nt], 0, 0, 0);
        acc[nt] = __builtin_amdgcn_mfma_f32_16x16x32_bf16(A1, Bv[0][nt], acc[nt], 0, 0, 0);
        acc[nt] = __builtin_amdgcn_mfma_f32_16x16x32_bf16(A1, Bv[1][nt], acc[nt], 0, 0, 0);
        acc[nt] = __builtin_amdgcn_mfma_f32_16x16x32_bf16(A0, Bv[2][nt], acc[nt], 0, 0, 0);
        acc[nt] = __builtin_amdgcn_mfma_f32_16x16x32_bf16(A2, Bv[0][nt], acc[nt], 0, 0, 0);
      }
      c0 = n0; c1 = n1; n0 = f0; n1 = f1;
    }
  };

  const int kw0 = kq * 576;
  if (kq < 3) {
    run(hrow + kw0, kw0, 18);            // pure h: 576 k
  } else {
    run(hrow + 1728, 1728, 10);          // h tail: [1728,2048)
    run(urow, 2048, 8);                  // u: [2048,2304)
  }

  // ---- 4-phase K reduce into slab (D: row=token=(lane>>4)*4+reg, col=mm) ----
  const int row = tw * 16 + (lane >> 4) * 4;
  for (int ph = 0; ph < 4; ++ph) {
    if (kq == ph) {
#pragma unroll
      for (int nt = 0; nt < 4; ++nt)
#pragma unroll
        for (int r = 0; r < 4; ++r) {
          float* p = &slab[(row + r) * LP + nt * 16 + mm];
          if (ph == 0) *p = acc[nt][r]; else *p += acc[nt][r];
        }
    }
    __syncthreads();
  }

  // ---- epilogue: wave wid handles tokens [4*wid, 4*wid+4); lane = expert ----
  const float bias = b[lane];
#pragma unroll
  for (int tt = 0; tt < 4; ++tt) {
    const int t = wid * 4 + tt;
    float g = slab[t * LP + lane] + bias;

    float m = g;
#pragma unroll
    for (int off = 32; off > 0; off >>= 1)
      m = fmaxf(m, __shfl_xor(m, off));
    float pexp = __expf(g - m);
    float s = pexp;
#pragma unroll
    for (int off = 32; off > 0; off >>= 1)
      s += __shfl_xor(s, off);
    const float pn = pexp / s;

    float vv = pn;
    float topsum = 0.f;
    int sel = 0;
    for (int r = 0; r < TOPK; ++r) {
      float mv = vv;
      int mi = lane;
#pragma unroll
      for (int off = 32; off > 0; off >>= 1) {
        const float ov = __shfl_xor(mv, off);
        const int oi = __shfl_xor(mi, off);
        if (ov > mv || (ov == mv && oi < mi)) { mv = ov; mi = oi; }
      }
      topsum += mv;
      if (lane == mi) { sel = 1; vv = -1.f; }
    }

    out[(size_t)(tok0 + t) * NE + lane] =
        sel ? pn / (topsum + 1e-9f) : 0.f;
  }
}

extern "C" void kernel_launch(void* const* d_in, const int* in_sizes, int n_in,
                              void* d_out, int out_size, void* d_ws, size_t ws_size,
                              hipStream_t stream) {
  const float* h = (const float*)d_in[0];
  const float* u = (const float*)d_in[1];
  const float* W = (const float*)d_in[2];
  const float* b = (const float*)d_in[3];
  float* out = (float*)d_out;

  unsigned short* wb = (unsigned short*)d_ws;  // 72*6144 shorts = 884736 B

  const int n_tokens = in_sizes[0] / EMB;  // 16384

  hipLaunchKernelGGL(prep_w, dim3(KTOT * NE / 256), dim3(256), 0, stream, W, wb);
  hipLaunchKernelGGL(gate_mfma, dim3(n_tokens / TPB), dim3(512), 0, stream,
                     h, u, wb, b, out);
}